// Round 6
// baseline (133.450 us; speedup 1.0000x reference)
//
#include <hip/hip_runtime.h>

#define B 16
#define C 128
#define NN 1024
#define KV 512
#define CHO 4

typedef _Float16 f16x8 __attribute__((ext_vector_type(8)));
typedef float f32x4 __attribute__((ext_vector_type(4)));

__device__ __forceinline__ unsigned short f2h(float v) {
  _Float16 h = (_Float16)v;
  return __builtin_bit_cast(unsigned short, h);
}
__device__ __forceinline__ unsigned int packh2(float a, float b) {
  return (unsigned int)f2h(a) | ((unsigned int)f2h(b) << 16);
}
__device__ __forceinline__ f16x8 ldcvt8(const float* __restrict__ p) {
  float4 a = *reinterpret_cast<const float4*>(p);
  float4 b = *reinterpret_cast<const float4*>(p + 4);
  f16x8 r;
  r[0] = (_Float16)a.x; r[1] = (_Float16)a.y; r[2] = (_Float16)a.z; r[3] = (_Float16)a.w;
  r[4] = (_Float16)b.x; r[5] = (_Float16)b.y; r[6] = (_Float16)b.z; r[7] = (_Float16)b.w;
  return r;
}
__device__ __forceinline__ f32x4 MFMA(f16x8 a, f16x8 b, f32x4 c) {
  return __builtin_amdgcn_mfma_f32_16x16x32_f16(a, b, c, 0, 0, 0);
}

// ---------------- K1: projections via f16 MFMA (unchanged; verified)
__global__ __launch_bounds__(256, 4) void proj_kernel(
    const float* __restrict__ x, const float* __restrict__ Wq,
    const float* __restrict__ Wk, const float* __restrict__ Wv,
    unsigned short* __restrict__ fT, unsigned short* __restrict__ gT,
    unsigned short* __restrict__ hv)
{
  int wg = blockIdx.x;
  wg = (wg & 7) * 384 + (wg >> 3);      // XCD cluster
  const int b   = wg / 192;
  const int rem = wg % 192;
  const int rt  = rem % 12;
  const int n0  = (rem / 12) * 64;

  __shared__ __align__(16) unsigned short XT[64][136];   // XT[n][c] f16

  const int t = threadIdx.x;
  const int w = t >> 6, l = t & 63, lg = l >> 4, lm = l & 15;

  {
    const float* xb = x + (size_t)b * C * NN;
    #pragma unroll
    for (int i = 0; i < 8; ++i) {
      int flat = t + i * 256;
      int c  = flat >> 4;
      int ng = flat & 15;
      float4 v = *reinterpret_cast<const float4*>(xb + (size_t)c * NN + n0 + ng * 4);
      XT[ng * 4 + 0][c] = f2h(v.x);
      XT[ng * 4 + 1][c] = f2h(v.y);
      XT[ng * 4 + 2][c] = f2h(v.z);
      XT[ng * 4 + 3][c] = f2h(v.w);
    }
  }
  __syncthreads();

  if (rt < 4) {
    const float* Wsrc = (rt < 2) ? Wq : Wk;
    unsigned short* dst = (rt < 2) ? fT : gT;
    const int c0 = (rt & 1) * 64;
    const int r  = c0 + 16 * w + lm;
    f16x8 af[4];
    #pragma unroll
    for (int c4 = 0; c4 < 4; ++c4)
      af[c4] = ldcvt8(Wsrc + (size_t)r * C + c4 * 32 + lg * 8);
    #pragma unroll
    for (int nt4 = 0; nt4 < 4; ++nt4) {
      f32x4 acc = {0.f, 0.f, 0.f, 0.f};
      #pragma unroll
      for (int c4 = 0; c4 < 4; ++c4) {
        f16x8 xb = *reinterpret_cast<const f16x8*>(&XT[16 * nt4 + lm][c4 * 32 + lg * 8]);
        acc = MFMA(af[c4], xb, acc);
      }
      int n = n0 + 16 * nt4 + lm;
      ushort4 o = { f2h(acc[0]), f2h(acc[1]), f2h(acc[2]), f2h(acc[3]) };
      *reinterpret_cast<ushort4*>(dst + ((size_t)(b * NN) + n) * C + c0 + 16 * w + 4 * lg) = o;
    }
  } else {
    const int kk = (rt - 4) * 64 + 16 * w + lm;
    f16x8 wb[4];
    #pragma unroll
    for (int c4 = 0; c4 < 4; ++c4)
      wb[c4] = ldcvt8(Wv + (size_t)kk * C + c4 * 32 + lg * 8);
    #pragma unroll
    for (int nt4 = 0; nt4 < 4; ++nt4) {
      f32x4 acc = {0.f, 0.f, 0.f, 0.f};
      #pragma unroll
      for (int c4 = 0; c4 < 4; ++c4) {
        f16x8 xa = *reinterpret_cast<const f16x8*>(&XT[16 * nt4 + lm][c4 * 32 + lg * 8]);
        acc = MFMA(xa, wb[c4], acc);
      }
      ushort4 o = { f2h(acc[0]), f2h(acc[1]), f2h(acc[2]), f2h(acc[3]) };
      *reinterpret_cast<ushort4*>(hv + ((size_t)(b * KV) + kk) * NN + n0 + 16 * nt4 + 4 * lg) = o;
    }
  }
}

// ---------------- helpers for K2 (compile-time NKT so all indexing is static)
template<int NKT>
__device__ __forceinline__ void rescale_acc(f32x4 (&acc)[5][4],
    float rr0, float rr1, float rr2, float rr3) {
  #pragma unroll
  for (int kt = 0; kt < NKT; ++kt) {
    acc[kt][0] *= rr0; acc[kt][1] *= rr1;
    acc[kt][2] *= rr2; acc[kt][3] *= rr3;
  }
}
template<int NKT>
__device__ __forceinline__ void pv_step(f32x4 (&acc)[5][4], const f16x8 (&vf)[5][2],
                                        const f16x8 (&pt)[4][2]) {
  #pragma unroll
  for (int kt = 0; kt < NKT; ++kt)
    #pragma unroll
    for (int mt = 0; mt < 4; ++mt) {
      acc[kt][mt] = MFMA(vf[kt][0], pt[mt][0], acc[kt][mt]);
      acc[kt][mt] = MFMA(vf[kt][1], pt[mt][1], acc[kt][mt]);
    }
}
template<int NKT>
__device__ __forceinline__ void vf_load(f16x8 (&vf)[5][2],
    const unsigned short* __restrict__ vp, int n0) {
  #pragma unroll
  for (int kt = 0; kt < NKT; ++kt) {
    vf[kt][0] = *reinterpret_cast<const f16x8*>(vp + (size_t)(16 * kt) * NN + n0);
    vf[kt][1] = *reinterpret_cast<const f16x8*>(vp + (size_t)(16 * kt) * NN + n0 + 32);
  }
}
template<int NKT>
__device__ __forceinline__ void store_out(const f32x4 (&acc)[5][4],
    const float* __restrict__ mask, float* __restrict__ out,
    const float (&scv)[4], int b, int m0, int lg, int lm, int kbase) {
  #pragma unroll
  for (int kt = 0; kt < NKT; ++kt)
    #pragma unroll
    for (int mt = 0; mt < 4; ++mt) {
      int m = m0 + 16 * mt + lm;
      #pragma unroll
      for (int reg = 0; reg < 4; ++reg) {
        int k  = kbase + 16 * kt + 4 * lg + reg;
        int oc = k & 127, ch = k >> 7;
        float v = acc[kt][mt][reg] * scv[mt] + mask[((size_t)oc * NN + m) * CHO + ch];
        out[(((size_t)(b * 128 + oc)) * NN + m) * CHO + ch] = v;
      }
    }
}

// ---------------- K2: MFMA flash attention, 8 waves producer/consumer.
// Block: 64 m-cols, 16 chunks of 64 n, parity double-buffered P, 1 barrier/chunk.
// Waves 0-3: QK+softmax for m-sub w (dup=1) + PV k-slice of 48 (kbase=48w).
// Waves 4-7: PV only, k-slice of 80 (kbase=192+80(w-4)).  48*4+80*4=512.
__global__ __launch_bounds__(512, 1) void attn_kernel(
    const unsigned short* __restrict__ fT, const unsigned short* __restrict__ gT,
    const unsigned short* __restrict__ hv, const float* __restrict__ gamma,
    const float* __restrict__ mask, float* __restrict__ out)
{
  int wg = blockIdx.x;
  wg = (wg & 7) * 32 + (wg >> 3);       // XCD cluster: 2 batches per XCD chunk
  const int b  = wg >> 4;
  const int m0 = (wg & 15) * 64;

  const int t = threadIdx.x;
  const int w = t >> 6, l = t & 63, lg = l >> 4, lm = l & 15;
  const int kbase = (w < 4) ? 48 * w : 192 + 80 * (w - 4);

  __shared__ __align__(16) unsigned short P_lds[2][64][72];  // [par][m][n] f16
  __shared__ float resc_s[2][64];
  __shared__ float lsum_s[64];

  // Q frags (QK waves only): B operand, lane holds gT[m0+16w+lm][c4*32+8lg+i]
  f16x8 qf[4];
  if (w < 4) {
    const unsigned short* qp = gT + ((size_t)(b * NN) + m0 + 16 * w + lm) * C + lg * 8;
    #pragma unroll
    for (int c4 = 0; c4 < 4; ++c4)
      qf[c4] = *reinterpret_cast<const f16x8*>(qp + c4 * 32);
  }

  f32x4 acc[5][4];  // [kt][mt]: k = kbase+16kt+4lg+reg, m = m0+16mt+lm
  #pragma unroll
  for (int kt = 0; kt < 5; ++kt)
    #pragma unroll
    for (int mt = 0; mt < 4; ++mt)
      acc[kt][mt] = (f32x4){0.f, 0.f, 0.f, 0.f};

  float M = -3.0e38f, Lpart = 0.f;

  const unsigned short* kp = fT + ((size_t)(b * NN) + lm) * C + lg * 8;
  const unsigned short* vp = hv + ((size_t)(b * KV) + kbase + lm) * NN + lg * 8;

  f16x8 vf[5][2];
  if (w < 4) vf_load<3>(vf, vp, 0); else vf_load<5>(vf, vp, 0);

  #pragma unroll 1
  for (int it = 0; it < 16; ++it) {
    const int n0  = it * 64;
    const int cur = it & 1;
    const int nx0 = ((it + 1) & 15) * 64;   // wraps harmlessly at it=15

    if (w < 4) {
      // QK^T (swapped): D[n][m-sub], K-frag loads inline (lifetime in this BB)
      f32x4 st[4];
      #pragma unroll
      for (int j = 0; j < 4; ++j) st[j] = (f32x4){0.f, 0.f, 0.f, 0.f};
      #pragma unroll
      for (int c4 = 0; c4 < 4; ++c4) {
        #pragma unroll
        for (int j = 0; j < 4; ++j) {
          f16x8 kf = *reinterpret_cast<const f16x8*>(kp + (size_t)(n0 + 16 * j) * C + c4 * 32);
          st[j] = MFMA(kf, qf[c4], st[j]);
        }
      }

      // online softmax over n (lane: n = n0+16j+4lg+reg, col m0+16w+lm)
      float cmax = -3.0e38f;
      #pragma unroll
      for (int j = 0; j < 4; ++j)
        cmax = fmaxf(cmax, fmaxf(fmaxf(st[j][0], st[j][1]), fmaxf(st[j][2], st[j][3])));
      cmax = fmaxf(cmax, __shfl_xor(cmax, 16, 64));
      cmax = fmaxf(cmax, __shfl_xor(cmax, 32, 64));
      float r = 1.0f;
      if (!__all(cmax <= M + 8.0f)) {       // T13 defer-rescale
        float newM = fmaxf(M, cmax);
        r = __expf(M - newM);
        M = newM;
        Lpart *= r;
      }
      float ls = 0.f;
      #pragma unroll
      for (int j = 0; j < 4; ++j) {        // exp in place (st becomes P)
        st[j][0] = __expf(st[j][0] - M);
        st[j][1] = __expf(st[j][1] - M);
        st[j][2] = __expf(st[j][2] - M);
        st[j][3] = __expf(st[j][3] - M);
        ls += (st[j][0] + st[j][1]) + (st[j][2] + st[j][3]);
      }
      Lpart += ls;
      if (lg == 0) resc_s[cur][16 * w + lm] = r;
      unsigned short* prow = &P_lds[cur][16 * w + lm][0];
      #pragma unroll
      for (int j = 0; j < 4; ++j) {
        *(unsigned int*)(prow + 16 * j + 4 * lg)     = packh2(st[j][0], st[j][1]);
        *(unsigned int*)(prow + 16 * j + 4 * lg + 2) = packh2(st[j][2], st[j][3]);
      }
    }
    __syncthreads();   // the ONLY barrier per chunk

    // all waves: rescale factors + P^T B-frags
    float rr0 = resc_s[cur][lm],      rr1 = resc_s[cur][16 + lm],
          rr2 = resc_s[cur][32 + lm], rr3 = resc_s[cur][48 + lm];
    f16x8 pt[4][2];
    #pragma unroll
    for (int mt = 0; mt < 4; ++mt) {
      pt[mt][0] = *reinterpret_cast<const f16x8*>(&P_lds[cur][16 * mt + lm][8 * lg]);
      pt[mt][1] = *reinterpret_cast<const f16x8*>(&P_lds[cur][16 * mt + lm][32 + 8 * lg]);
    }
    bool needr = !__all((rr0 == 1.f) & (rr1 == 1.f) & (rr2 == 1.f) & (rr3 == 1.f));

    if (w < 4) {
      if (needr) rescale_acc<3>(acc, rr0, rr1, rr2, rr3);
      pv_step<3>(acc, vf, pt);
      vf_load<3>(vf, vp, nx0);             // latency hidden under next QK+softmax
    } else {
      if (needr) rescale_acc<5>(acc, rr0, rr1, rr2, rr3);
      pv_step<5>(acc, vf, pt);
      vf_load<5>(vf, vp, nx0);
    }
  }

  // denominators (QK waves own them); broadcast via LDS
  float Lp = Lpart;
  Lp += __shfl_xor(Lp, 16, 64);
  Lp += __shfl_xor(Lp, 32, 64);
  __syncthreads();
  if (w < 4 && lg == 0) lsum_s[16 * w + lm] = Lp;
  __syncthreads();

  const float gam = gamma[0];
  float scv[4] = { gam / lsum_s[lm],      gam / lsum_s[16 + lm],
                   gam / lsum_s[32 + lm], gam / lsum_s[48 + lm] };

  if (w < 4) store_out<3>(acc, mask, out, scv, b, m0, lg, lm, kbase);
  else       store_out<5>(acc, mask, out, scv, b, m0, lg, lm, kbase);
}

extern "C" void kernel_launch(void* const* d_in, const int* in_sizes, int n_in,
                              void* d_out, int out_size, void* d_ws, size_t ws_size,
                              hipStream_t stream) {
  const float* x     = (const float*)d_in[0];
  const float* Wq    = (const float*)d_in[1];
  const float* Wk    = (const float*)d_in[2];
  const float* Wv    = (const float*)d_in[3];
  const float* gamma = (const float*)d_in[4];
  const float* mask  = (const float*)d_in[5];
  float* out = (float*)d_out;

  unsigned short* fT = (unsigned short*)d_ws;                 // [B][NN][C]  f16
  unsigned short* gT = fT + (size_t)B * NN * C;               // [B][NN][C]  f16
  unsigned short* hv = gT + (size_t)B * NN * C;               // [B][KV][NN] f16

  proj_kernel<<<dim3(3072), 256, 0, stream>>>(x, Wq, Wk, Wv, fT, gT, hv);
  attn_kernel<<<dim3(256), 512, 0, stream>>>(fT, gT, hv, gamma, mask, out);
}

// Round 7
// 125.953 us; speedup vs baseline: 1.0595x; 1.0595x over previous
//
#include <hip/hip_runtime.h>

#define B 16
#define C 128
#define NN 1024
#define KV 512
#define CHO 4

typedef _Float16 f16x8 __attribute__((ext_vector_type(8)));
typedef float f32x4 __attribute__((ext_vector_type(4)));

__device__ __forceinline__ unsigned short f2h(float v) {
  _Float16 h = (_Float16)v;
  return __builtin_bit_cast(unsigned short, h);
}
__device__ __forceinline__ unsigned int packh2(float a, float b) {
  return (unsigned int)f2h(a) | ((unsigned int)f2h(b) << 16);
}
__device__ __forceinline__ f16x8 ldcvt8(const float* __restrict__ p) {
  float4 a = *reinterpret_cast<const float4*>(p);
  float4 b = *reinterpret_cast<const float4*>(p + 4);
  f16x8 r;
  r[0] = (_Float16)a.x; r[1] = (_Float16)a.y; r[2] = (_Float16)a.z; r[3] = (_Float16)a.w;
  r[4] = (_Float16)b.x; r[5] = (_Float16)b.y; r[6] = (_Float16)b.z; r[7] = (_Float16)b.w;
  return r;
}
__device__ __forceinline__ f32x4 MFMA(f16x8 a, f16x8 b, f32x4 c) {
  return __builtin_amdgcn_mfma_f32_16x16x32_f16(a, b, c, 0, 0, 0);
}

// ---------------- K1: projections via f16 MFMA (unchanged; verified)
__global__ __launch_bounds__(256, 4) void proj_kernel(
    const float* __restrict__ x, const float* __restrict__ Wq,
    const float* __restrict__ Wk, const float* __restrict__ Wv,
    unsigned short* __restrict__ fT, unsigned short* __restrict__ gT,
    unsigned short* __restrict__ hv)
{
  int wg = blockIdx.x;
  wg = (wg & 7) * 384 + (wg >> 3);      // XCD cluster
  const int b   = wg / 192;
  const int rem = wg % 192;
  const int rt  = rem % 12;
  const int n0  = (rem / 12) * 64;

  __shared__ __align__(16) unsigned short XT[64][136];   // XT[n][c] f16

  const int t = threadIdx.x;
  const int w = t >> 6, l = t & 63, lg = l >> 4, lm = l & 15;

  {
    const float* xb = x + (size_t)b * C * NN;
    #pragma unroll
    for (int i = 0; i < 8; ++i) {
      int flat = t + i * 256;
      int c  = flat >> 4;
      int ng = flat & 15;
      float4 v = *reinterpret_cast<const float4*>(xb + (size_t)c * NN + n0 + ng * 4);
      XT[ng * 4 + 0][c] = f2h(v.x);
      XT[ng * 4 + 1][c] = f2h(v.y);
      XT[ng * 4 + 2][c] = f2h(v.z);
      XT[ng * 4 + 3][c] = f2h(v.w);
    }
  }
  __syncthreads();

  if (rt < 4) {
    const float* Wsrc = (rt < 2) ? Wq : Wk;
    unsigned short* dst = (rt < 2) ? fT : gT;
    const int c0 = (rt & 1) * 64;
    const int r  = c0 + 16 * w + lm;
    f16x8 af[4];
    #pragma unroll
    for (int c4 = 0; c4 < 4; ++c4)
      af[c4] = ldcvt8(Wsrc + (size_t)r * C + c4 * 32 + lg * 8);
    #pragma unroll
    for (int nt4 = 0; nt4 < 4; ++nt4) {
      f32x4 acc = {0.f, 0.f, 0.f, 0.f};
      #pragma unroll
      for (int c4 = 0; c4 < 4; ++c4) {
        f16x8 xb = *reinterpret_cast<const f16x8*>(&XT[16 * nt4 + lm][c4 * 32 + lg * 8]);
        acc = MFMA(af[c4], xb, acc);
      }
      int n = n0 + 16 * nt4 + lm;
      ushort4 o = { f2h(acc[0]), f2h(acc[1]), f2h(acc[2]), f2h(acc[3]) };
      *reinterpret_cast<ushort4*>(dst + ((size_t)(b * NN) + n) * C + c0 + 16 * w + 4 * lg) = o;
    }
  } else {
    const int kk = (rt - 4) * 64 + 16 * w + lm;
    f16x8 wb[4];
    #pragma unroll
    for (int c4 = 0; c4 < 4; ++c4)
      wb[c4] = ldcvt8(Wv + (size_t)kk * C + c4 * 32 + lg * 8);
    #pragma unroll
    for (int nt4 = 0; nt4 < 4; ++nt4) {
      f32x4 acc = {0.f, 0.f, 0.f, 0.f};
      #pragma unroll
      for (int c4 = 0; c4 < 4; ++c4) {
        f16x8 xa = *reinterpret_cast<const f16x8*>(&XT[16 * nt4 + lm][c4 * 32 + lg * 8]);
        acc = MFMA(xa, wb[c4], acc);
      }
      ushort4 o = { f2h(acc[0]), f2h(acc[1]), f2h(acc[2]), f2h(acc[3]) };
      *reinterpret_cast<ushort4*>(hv + ((size_t)(b * KV) + kk) * NN + n0 + 16 * nt4 + 4 * lg) = o;
    }
  }
}

// ---------------- K2: MFMA flash attention, 8 waves = 2 independent n-groups
// Block: 64 m-cols. Group g (waves 4g..4g+3) handles n in [512g, 512g+512),
// running the verified R5 loop (8 chunks of 64 n, parity-buffered P, one
// barrier/chunk). Within a group, wave wl: QK+softmax owner of m-sub wl AND
// PV k-slice [128wl, 128wl+128). End: flash-merge of the two groups via LDS
// stats + out RMW (same CU/L2, barrier-ordered).
__global__ __launch_bounds__(512, 2) void attn_kernel(
    const unsigned short* __restrict__ fT, const unsigned short* __restrict__ gT,
    const unsigned short* __restrict__ hv, const float* __restrict__ gamma,
    const float* __restrict__ mask, float* __restrict__ out)
{
  int wg = blockIdx.x;
  wg = (wg & 7) * 32 + (wg >> 3);       // XCD cluster: 2 batches per XCD
  const int b  = wg >> 4;
  const int m0 = (wg & 15) * 64;

  const int t = threadIdx.x;
  const int w = t >> 6, l = t & 63, lg = l >> 4, lm = l & 15;
  const int g = w >> 2, wl = w & 3;

  __shared__ __align__(16) unsigned short P_lds[2][2][64][72];  // [g][par][m][n]
  __shared__ float resc_s[2][2][64];
  __shared__ float gM[2][64];
  __shared__ float gL[2][64];

  // Q frags: B operand, lane holds gT[m0+16wl+lm][c4*32+8lg+i] (same for both g)
  f16x8 qf[4];
  {
    const unsigned short* qp = gT + ((size_t)(b * NN) + m0 + 16 * wl + lm) * C + lg * 8;
    #pragma unroll
    for (int c4 = 0; c4 < 4; ++c4)
      qf[c4] = *reinterpret_cast<const f16x8*>(qp + c4 * 32);
  }

  f32x4 acc[8][4];  // [kt][mt]: k = 128wl+16kt+4lg+reg, m = m0+16mt+lm
  #pragma unroll
  for (int kt = 0; kt < 8; ++kt)
    #pragma unroll
    for (int mt = 0; mt < 4; ++mt)
      acc[kt][mt] = (f32x4){0.f, 0.f, 0.f, 0.f};

  float M = -3.0e38f, Lpart = 0.f;

  const unsigned short* kp = fT + ((size_t)(b * NN) + lm) * C + lg * 8;
  const unsigned short* vp = hv + ((size_t)(b * KV) + 128 * wl + lm) * NN + lg * 8;
  const int nbase = g * 512;

  #pragma unroll 1
  for (int it = 0; it < 8; ++it) {
    const int n0  = nbase + it * 64;
    const int cur = it & 1;

    // QK^T (swapped): D[n][m-sub], K-frag loads inline
    f32x4 st[4];
    #pragma unroll
    for (int j = 0; j < 4; ++j) st[j] = (f32x4){0.f, 0.f, 0.f, 0.f};
    #pragma unroll
    for (int c4 = 0; c4 < 4; ++c4) {
      #pragma unroll
      for (int j = 0; j < 4; ++j) {
        f16x8 kf = *reinterpret_cast<const f16x8*>(kp + (size_t)(n0 + 16 * j) * C + c4 * 32);
        st[j] = MFMA(kf, qf[c4], st[j]);
      }
    }

    // online softmax over n (lane: n = n0+16j+4lg+reg, col m0+16wl+lm)
    float cmax = -3.0e38f;
    #pragma unroll
    for (int j = 0; j < 4; ++j)
      cmax = fmaxf(cmax, fmaxf(fmaxf(st[j][0], st[j][1]), fmaxf(st[j][2], st[j][3])));
    cmax = fmaxf(cmax, __shfl_xor(cmax, 16, 64));
    cmax = fmaxf(cmax, __shfl_xor(cmax, 32, 64));
    float r = 1.0f;
    if (!__all(cmax <= M + 8.0f)) {       // T13 defer-rescale
      float newM = fmaxf(M, cmax);
      r = __expf(M - newM);
      M = newM;
      Lpart *= r;
    }
    float ls = 0.f;
    #pragma unroll
    for (int j = 0; j < 4; ++j) {        // exp in place (st becomes P)
      st[j][0] = __expf(st[j][0] - M);
      st[j][1] = __expf(st[j][1] - M);
      st[j][2] = __expf(st[j][2] - M);
      st[j][3] = __expf(st[j][3] - M);
      ls += (st[j][0] + st[j][1]) + (st[j][2] + st[j][3]);
    }
    Lpart += ls;
    if (lg == 0) resc_s[g][cur][16 * wl + lm] = r;
    {
      unsigned short* prow = &P_lds[g][cur][16 * wl + lm][0];
      #pragma unroll
      for (int j = 0; j < 4; ++j) {
        *(unsigned int*)(prow + 16 * j + 4 * lg)     = packh2(st[j][0], st[j][1]);
        *(unsigned int*)(prow + 16 * j + 4 * lg + 2) = packh2(st[j][2], st[j][3]);
      }
    }
    __syncthreads();   // the ONLY barrier per chunk

    // rescale factors
    float rr0 = resc_s[g][cur][lm],      rr1 = resc_s[g][cur][16 + lm],
          rr2 = resc_s[g][cur][32 + lm], rr3 = resc_s[g][cur][48 + lm];
    if (!__all((rr0 == 1.f) & (rr1 == 1.f) & (rr2 == 1.f) & (rr3 == 1.f))) {
      #pragma unroll
      for (int kt = 0; kt < 8; ++kt) {
        acc[kt][0] *= rr0; acc[kt][1] *= rr1;
        acc[kt][2] *= rr2; acc[kt][3] *= rr3;
      }
    }

    // PV in two k-halves (register peak control): per half, V frags + P frags
    #pragma unroll
    for (int h = 0; h < 2; ++h) {
      f16x8 vfh[4];
      #pragma unroll
      for (int kt = 0; kt < 4; ++kt)
        vfh[kt] = *reinterpret_cast<const f16x8*>(vp + (size_t)(16 * (4 * h + kt)) * NN + n0);
      f16x8 vfh2[4];
      #pragma unroll
      for (int kt = 0; kt < 4; ++kt)
        vfh2[kt] = *reinterpret_cast<const f16x8*>(vp + (size_t)(16 * (4 * h + kt)) * NN + n0 + 32);
      f16x8 pth[4][2];
      #pragma unroll
      for (int mt = 0; mt < 4; ++mt) {
        pth[mt][0] = *reinterpret_cast<const f16x8*>(&P_lds[g][cur][16 * mt + lm][8 * lg]);
        pth[mt][1] = *reinterpret_cast<const f16x8*>(&P_lds[g][cur][16 * mt + lm][32 + 8 * lg]);
      }
      #pragma unroll
      for (int kt = 0; kt < 4; ++kt)
        #pragma unroll
        for (int mt = 0; mt < 4; ++mt) {
          acc[4 * h + kt][mt] = MFMA(vfh[kt],  pth[mt][0], acc[4 * h + kt][mt]);
          acc[4 * h + kt][mt] = MFMA(vfh2[kt], pth[mt][1], acc[4 * h + kt][mt]);
        }
    }
    // no trailing barrier: next chunk writes the other parity buffers
  }

  // group-local denominators -> LDS stats
  float Lp = Lpart;
  Lp += __shfl_xor(Lp, 16, 64);
  Lp += __shfl_xor(Lp, 32, 64);
  __syncthreads();
  if (lg == 0) { gM[g][16 * wl + lm] = M; gL[g][16 * wl + lm] = Lp; }
  __syncthreads();

  // flash-merge weights per m-column
  const float gam = gamma[0];
  float sc[4];
  #pragma unroll
  for (int mt = 0; mt < 4; ++mt) {
    int mloc = 16 * mt + lm;
    float M0 = gM[0][mloc], M1 = gM[1][mloc];
    float L0 = gL[0][mloc], L1 = gL[1][mloc];
    float Mx = fmaxf(M0, M1);
    float e0 = __expf(M0 - Mx), e1 = __expf(M1 - Mx);
    float D  = L0 * e0 + L1 * e1;
    sc[mt] = gam * ((g == 0) ? e0 : e1) / D;
  }

  // group 1 stores its weighted partial; then group 0 RMWs + mask
  if (g == 1) {
    #pragma unroll
    for (int kt = 0; kt < 8; ++kt)
      #pragma unroll
      for (int mt = 0; mt < 4; ++mt) {
        int m = m0 + 16 * mt + lm;
        #pragma unroll
        for (int reg = 0; reg < 4; ++reg) {
          int k  = 128 * wl + 16 * kt + 4 * lg + reg;
          int oc = k & 127, ch = k >> 7;
          out[(((size_t)(b * 128 + oc)) * NN + m) * CHO + ch] = acc[kt][mt][reg] * sc[mt];
        }
      }
  }
  __syncthreads();   // drains g1 stores (vmcnt) before g0 reads
  if (g == 0) {
    #pragma unroll
    for (int kt = 0; kt < 8; ++kt)
      #pragma unroll
      for (int mt = 0; mt < 4; ++mt) {
        int m = m0 + 16 * mt + lm;
        #pragma unroll
        for (int reg = 0; reg < 4; ++reg) {
          int k  = 128 * wl + 16 * kt + 4 * lg + reg;
          int oc = k & 127, ch = k >> 7;
          size_t oidx = (((size_t)(b * 128 + oc)) * NN + m) * CHO + ch;
          out[oidx] = out[oidx] + acc[kt][mt][reg] * sc[mt]
                    + mask[((size_t)oc * NN + m) * CHO + ch];
        }
      }
  }
}

extern "C" void kernel_launch(void* const* d_in, const int* in_sizes, int n_in,
                              void* d_out, int out_size, void* d_ws, size_t ws_size,
                              hipStream_t stream) {
  const float* x     = (const float*)d_in[0];
  const float* Wq    = (const float*)d_in[1];
  const float* Wk    = (const float*)d_in[2];
  const float* Wv    = (const float*)d_in[3];
  const float* gamma = (const float*)d_in[4];
  const float* mask  = (const float*)d_in[5];
  float* out = (float*)d_out;

  unsigned short* fT = (unsigned short*)d_ws;                 // [B][NN][C]  f16
  unsigned short* gT = fT + (size_t)B * NN * C;               // [B][NN][C]  f16
  unsigned short* hv = gT + (size_t)B * NN * C;               // [B][KV][NN] f16

  proj_kernel<<<dim3(3072), 256, 0, stream>>>(x, Wq, Wk, Wv, fT, gT, hv);
  attn_kernel<<<dim3(256), 512, 0, stream>>>(fT, gT, hv, gamma, mask, out);
}

// Round 8
// 112.530 us; speedup vs baseline: 1.1859x; 1.1193x over previous
//
#include <hip/hip_runtime.h>

#define B 16
#define C 128
#define NN 1024
#define KV 512
#define CHO 4

typedef _Float16 f16x8 __attribute__((ext_vector_type(8)));
typedef float f32x4 __attribute__((ext_vector_type(4)));

__device__ __forceinline__ unsigned short f2h(float v) {
  _Float16 h = (_Float16)v;
  return __builtin_bit_cast(unsigned short, h);
}
__device__ __forceinline__ unsigned int packh2(float a, float b) {
  return (unsigned int)f2h(a) | ((unsigned int)f2h(b) << 16);
}
__device__ __forceinline__ f16x8 ldcvt8(const float* __restrict__ p) {
  float4 a = *reinterpret_cast<const float4*>(p);
  float4 b = *reinterpret_cast<const float4*>(p + 4);
  f16x8 r;
  r[0] = (_Float16)a.x; r[1] = (_Float16)a.y; r[2] = (_Float16)a.z; r[3] = (_Float16)a.w;
  r[4] = (_Float16)b.x; r[5] = (_Float16)b.y; r[6] = (_Float16)b.z; r[7] = (_Float16)b.w;
  return r;
}
__device__ __forceinline__ f32x4 MFMA(f16x8 a, f16x8 b, f32x4 c) {
  return __builtin_amdgcn_mfma_f32_16x16x32_f16(a, b, c, 0, 0, 0);
}

// ---------------- K1: projections via f16 MFMA (unchanged; verified)
__global__ __launch_bounds__(256, 4) void proj_kernel(
    const float* __restrict__ x, const float* __restrict__ Wq,
    const float* __restrict__ Wk, const float* __restrict__ Wv,
    unsigned short* __restrict__ fT, unsigned short* __restrict__ gT,
    unsigned short* __restrict__ hv)
{
  int wg = blockIdx.x;
  wg = (wg & 7) * 384 + (wg >> 3);      // XCD cluster
  const int b   = wg / 192;
  const int rem = wg % 192;
  const int rt  = rem % 12;
  const int n0  = (rem / 12) * 64;

  __shared__ __align__(16) unsigned short XT[64][136];   // XT[n][c] f16

  const int t = threadIdx.x;
  const int w = t >> 6, l = t & 63, lg = l >> 4, lm = l & 15;

  {
    const float* xb = x + (size_t)b * C * NN;
    #pragma unroll
    for (int i = 0; i < 8; ++i) {
      int flat = t + i * 256;
      int c  = flat >> 4;
      int ng = flat & 15;
      float4 v = *reinterpret_cast<const float4*>(xb + (size_t)c * NN + n0 + ng * 4);
      XT[ng * 4 + 0][c] = f2h(v.x);
      XT[ng * 4 + 1][c] = f2h(v.y);
      XT[ng * 4 + 2][c] = f2h(v.z);
      XT[ng * 4 + 3][c] = f2h(v.w);
    }
  }
  __syncthreads();

  if (rt < 4) {
    const float* Wsrc = (rt < 2) ? Wq : Wk;
    unsigned short* dst = (rt < 2) ? fT : gT;
    const int c0 = (rt & 1) * 64;
    const int r  = c0 + 16 * w + lm;
    f16x8 af[4];
    #pragma unroll
    for (int c4 = 0; c4 < 4; ++c4)
      af[c4] = ldcvt8(Wsrc + (size_t)r * C + c4 * 32 + lg * 8);
    #pragma unroll
    for (int nt4 = 0; nt4 < 4; ++nt4) {
      f32x4 acc = {0.f, 0.f, 0.f, 0.f};
      #pragma unroll
      for (int c4 = 0; c4 < 4; ++c4) {
        f16x8 xb = *reinterpret_cast<const f16x8*>(&XT[16 * nt4 + lm][c4 * 32 + lg * 8]);
        acc = MFMA(af[c4], xb, acc);
      }
      int n = n0 + 16 * nt4 + lm;
      ushort4 o = { f2h(acc[0]), f2h(acc[1]), f2h(acc[2]), f2h(acc[3]) };
      *reinterpret_cast<ushort4*>(dst + ((size_t)(b * NN) + n) * C + c0 + 16 * w + 4 * lg) = o;
    }
  } else {
    const int kk = (rt - 4) * 64 + 16 * w + lm;
    f16x8 wb[4];
    #pragma unroll
    for (int c4 = 0; c4 < 4; ++c4)
      wb[c4] = ldcvt8(Wv + (size_t)kk * C + c4 * 32 + lg * 8);
    #pragma unroll
    for (int nt4 = 0; nt4 < 4; ++nt4) {
      f32x4 acc = {0.f, 0.f, 0.f, 0.f};
      #pragma unroll
      for (int c4 = 0; c4 < 4; ++c4) {
        f16x8 xa = *reinterpret_cast<const f16x8*>(&XT[16 * nt4 + lm][c4 * 32 + lg * 8]);
        acc = MFMA(xa, wb[c4], acc);
      }
      ushort4 o = { f2h(acc[0]), f2h(acc[1]), f2h(acc[2]), f2h(acc[3]) };
      *reinterpret_cast<ushort4*>(hv + ((size_t)(b * KV) + kk) * NN + n0 + 16 * nt4 + 4 * lg) = o;
    }
  }
}

// ---------------- K2: software-pipelined MFMA flash attention (R5 skeleton)
// 4 waves, 64 m-cols, 16 chunks of 64 n, parity P, 1 barrier/chunk.
// Pipelining: kf regs hold K(it+1) (loaded 1 body early); vfA/vfB double-
// buffer V; all global loads issued >= one MFMA-phase before their consumer.
template<int CUR, bool LAST>
__device__ __forceinline__ void attn_body(
    int it, f32x4 (&acc)[8][4], const f16x8 (&qf)[4], f16x8 (&kf)[4][4],
    f16x8 (&vfT)[8][2], f16x8 (&vfO)[8][2],
    unsigned short (&P_lds)[2][64][72], float (&resc_s)[2][64],
    const unsigned short* __restrict__ kp, const unsigned short* __restrict__ vp,
    float& M, float& Lpart, int w, int lg, int lm)
{
  constexpr int NXT = CUR ^ 1;

  // 1) P frags for chunk it + rescale factors (made visible by prev barrier)
  f16x8 pt[4][2];
  #pragma unroll
  for (int mt = 0; mt < 4; ++mt) {
    pt[mt][0] = *reinterpret_cast<const f16x8*>(&P_lds[CUR][16 * mt + lm][8 * lg]);
    pt[mt][1] = *reinterpret_cast<const f16x8*>(&P_lds[CUR][16 * mt + lm][32 + 8 * lg]);
  }
  float rr0 = resc_s[CUR][lm],      rr1 = resc_s[CUR][16 + lm],
        rr2 = resc_s[CUR][32 + lm], rr3 = resc_s[CUR][48 + lm];
  if (!__all((rr0 == 1.f) & (rr1 == 1.f) & (rr2 == 1.f) & (rr3 == 1.f))) {
    #pragma unroll
    for (int kt = 0; kt < 8; ++kt) {
      acc[kt][0] *= rr0; acc[kt][1] *= rr1;
      acc[kt][2] *= rr2; acc[kt][3] *= rr3;
    }
  }

  // 2) issue V loads for chunk it+1 into the other buffer (latency under PV)
  if (!LAST) {
    const int nv = ((it + 1) & 15) * 64;
    #pragma unroll
    for (int kt = 0; kt < 8; ++kt) {
      vfO[kt][0] = *reinterpret_cast<const f16x8*>(vp + (size_t)(16 * kt) * NN + nv);
      vfO[kt][1] = *reinterpret_cast<const f16x8*>(vp + (size_t)(16 * kt) * NN + nv + 32);
    }
  }

  // 3) PV for chunk it: 64 MFMA (covers V_next latency + finishes kf arrival)
  #pragma unroll
  for (int kt = 0; kt < 8; ++kt)
    #pragma unroll
    for (int mt = 0; mt < 4; ++mt) {
      acc[kt][mt] = MFMA(vfT[kt][0], pt[mt][0], acc[kt][mt]);
      acc[kt][mt] = MFMA(vfT[kt][1], pt[mt][1], acc[kt][mt]);
    }

  if (!LAST) {
    // 4) QK^T for chunk it+1 from prefetched kf (swapped: D[n][m-sub w])
    f32x4 st[4];
    #pragma unroll
    for (int j = 0; j < 4; ++j) st[j] = (f32x4){0.f, 0.f, 0.f, 0.f};
    #pragma unroll
    for (int c4 = 0; c4 < 4; ++c4)
      #pragma unroll
      for (int j = 0; j < 4; ++j)
        st[j] = MFMA(kf[j][c4], qf[c4], st[j]);

    // 5) refill kf with K(it+2) (latency under softmax + barrier + next PV)
    {
      const int nk = ((it + 2) & 15) * 64;
      #pragma unroll
      for (int j = 0; j < 4; ++j)
        #pragma unroll
        for (int c4 = 0; c4 < 4; ++c4)
          kf[j][c4] = *reinterpret_cast<const f16x8*>(kp + (size_t)(nk + 16 * j) * C + c4 * 32);
    }

    // 6) online softmax for chunk it+1 -> P_lds[NXT], resc_s[NXT]
    float cmax = -3.0e38f;
    #pragma unroll
    for (int j = 0; j < 4; ++j)
      cmax = fmaxf(cmax, fmaxf(fmaxf(st[j][0], st[j][1]), fmaxf(st[j][2], st[j][3])));
    cmax = fmaxf(cmax, __shfl_xor(cmax, 16, 64));
    cmax = fmaxf(cmax, __shfl_xor(cmax, 32, 64));
    float r = 1.0f;
    if (!__all(cmax <= M + 8.0f)) {       // T13 defer-rescale
      float newM = fmaxf(M, cmax);
      r = __expf(M - newM);
      M = newM;
      Lpart *= r;
    }
    float ls = 0.f;
    #pragma unroll
    for (int j = 0; j < 4; ++j) {
      st[j][0] = __expf(st[j][0] - M);
      st[j][1] = __expf(st[j][1] - M);
      st[j][2] = __expf(st[j][2] - M);
      st[j][3] = __expf(st[j][3] - M);
      ls += (st[j][0] + st[j][1]) + (st[j][2] + st[j][3]);
    }
    Lpart += ls;
    if (lg == 0) resc_s[NXT][16 * w + lm] = r;
    unsigned short* prow = &P_lds[NXT][16 * w + lm][0];
    #pragma unroll
    for (int j = 0; j < 4; ++j) {
      *(unsigned int*)(prow + 16 * j + 4 * lg)     = packh2(st[j][0], st[j][1]);
      *(unsigned int*)(prow + 16 * j + 4 * lg + 2) = packh2(st[j][2], st[j][3]);
    }
  }
  __syncthreads();
}

__global__ __launch_bounds__(256, 1) void attn_kernel(
    const unsigned short* __restrict__ fT, const unsigned short* __restrict__ gT,
    const unsigned short* __restrict__ hv, const float* __restrict__ gamma,
    const float* __restrict__ mask, float* __restrict__ out)
{
  int wg = blockIdx.x;
  wg = (wg & 7) * 32 + (wg >> 3);       // XCD cluster: 2 batches per XCD chunk
  const int b  = wg >> 4;
  const int m0 = (wg & 15) * 64;

  const int t = threadIdx.x;
  const int w = t >> 6, l = t & 63, lg = l >> 4, lm = l & 15;

  __shared__ __align__(16) unsigned short P_lds[2][64][72];  // [par][m][n] f16
  __shared__ float resc_s[2][64];
  __shared__ float lsum_s[64];

  // Q frags: B operand, lane holds gT[m0+16w+lm][c4*32+8lg+i]
  f16x8 qf[4];
  {
    const unsigned short* qp = gT + ((size_t)(b * NN) + m0 + 16 * w + lm) * C + lg * 8;
    #pragma unroll
    for (int c4 = 0; c4 < 4; ++c4)
      qf[c4] = *reinterpret_cast<const f16x8*>(qp + c4 * 32);
  }

  f32x4 acc[8][4];  // [kt][mt]: k = 128w+16kt+4lg+reg, m = m0+16mt+lm
  #pragma unroll
  for (int kt = 0; kt < 8; ++kt)
    #pragma unroll
    for (int mt = 0; mt < 4; ++mt)
      acc[kt][mt] = (f32x4){0.f, 0.f, 0.f, 0.f};

  float M = -3.0e38f, Lpart = 0.f;

  const unsigned short* kp = fT + ((size_t)(b * NN) + lm) * C + lg * 8;
  const unsigned short* vp = hv + ((size_t)(b * KV) + 128 * w + lm) * NN + lg * 8;

  f16x8 kf[4][4];     // K frags for the NEXT chunk to be QK'd
  f16x8 vfA[8][2], vfB[8][2];

  // ---- prologue: chunk 0 QK+softmax; prefetch K1, V0
  #pragma unroll
  for (int j = 0; j < 4; ++j)
    #pragma unroll
    for (int c4 = 0; c4 < 4; ++c4)
      kf[j][c4] = *reinterpret_cast<const f16x8*>(kp + (size_t)(16 * j) * C + c4 * 32);
  #pragma unroll
  for (int kt = 0; kt < 8; ++kt) {
    vfA[kt][0] = *reinterpret_cast<const f16x8*>(vp + (size_t)(16 * kt) * NN);
    vfA[kt][1] = *reinterpret_cast<const f16x8*>(vp + (size_t)(16 * kt) * NN + 32);
  }
  {
    f32x4 st[4];
    #pragma unroll
    for (int j = 0; j < 4; ++j) st[j] = (f32x4){0.f, 0.f, 0.f, 0.f};
    #pragma unroll
    for (int c4 = 0; c4 < 4; ++c4)
      #pragma unroll
      for (int j = 0; j < 4; ++j)
        st[j] = MFMA(kf[j][c4], qf[c4], st[j]);

    // refill kf with K(1) while softmax runs
    #pragma unroll
    for (int j = 0; j < 4; ++j)
      #pragma unroll
      for (int c4 = 0; c4 < 4; ++c4)
        kf[j][c4] = *reinterpret_cast<const f16x8*>(kp + (size_t)(64 + 16 * j) * C + c4 * 32);

    float cmax = -3.0e38f;
    #pragma unroll
    for (int j = 0; j < 4; ++j)
      cmax = fmaxf(cmax, fmaxf(fmaxf(st[j][0], st[j][1]), fmaxf(st[j][2], st[j][3])));
    cmax = fmaxf(cmax, __shfl_xor(cmax, 16, 64));
    cmax = fmaxf(cmax, __shfl_xor(cmax, 32, 64));
    float newM = fmaxf(M, cmax);
    float r = __expf(M - newM);    // = 0 (M = -inf)
    M = newM;
    Lpart *= r;
    float ls = 0.f;
    #pragma unroll
    for (int j = 0; j < 4; ++j) {
      st[j][0] = __expf(st[j][0] - M);
      st[j][1] = __expf(st[j][1] - M);
      st[j][2] = __expf(st[j][2] - M);
      st[j][3] = __expf(st[j][3] - M);
      ls += (st[j][0] + st[j][1]) + (st[j][2] + st[j][3]);
    }
    Lpart += ls;
    if (lg == 0) resc_s[0][16 * w + lm] = r;
    unsigned short* prow = &P_lds[0][16 * w + lm][0];
    #pragma unroll
    for (int j = 0; j < 4; ++j) {
      *(unsigned int*)(prow + 16 * j + 4 * lg)     = packh2(st[j][0], st[j][1]);
      *(unsigned int*)(prow + 16 * j + 4 * lg + 2) = packh2(st[j][2], st[j][3]);
    }
  }
  __syncthreads();

  // ---- pipelined main loop: 16 bodies (14 in 7 pairs + 2 peeled)
  #pragma unroll 1
  for (int it2 = 0; it2 < 7; ++it2) {
    attn_body<0, false>(2 * it2,     acc, qf, kf, vfA, vfB, P_lds, resc_s, kp, vp, M, Lpart, w, lg, lm);
    attn_body<1, false>(2 * it2 + 1, acc, qf, kf, vfB, vfA, P_lds, resc_s, kp, vp, M, Lpart, w, lg, lm);
  }
  attn_body<0, false>(14, acc, qf, kf, vfA, vfB, P_lds, resc_s, kp, vp, M, Lpart, w, lg, lm);
  attn_body<1, true >(15, acc, qf, kf, vfB, vfA, P_lds, resc_s, kp, vp, M, Lpart, w, lg, lm);

  // denominators
  float Lp = Lpart;
  Lp += __shfl_xor(Lp, 16, 64);
  Lp += __shfl_xor(Lp, 32, 64);
  if (lg == 0) lsum_s[16 * w + lm] = Lp;
  __syncthreads();

  const float gam = gamma[0];
  float scv[4] = { gam / lsum_s[lm],      gam / lsum_s[16 + lm],
                   gam / lsum_s[32 + lm], gam / lsum_s[48 + lm] };

  // out[b][oc][m][ch] + mask[oc][m][ch];  k = 128w+16kt+4lg+reg -> oc=k&127, ch=w
  #pragma unroll
  for (int kt = 0; kt < 8; ++kt) {
    #pragma unroll
    for (int mt = 0; mt < 4; ++mt) {
      int m = m0 + 16 * mt + lm;
      #pragma unroll
      for (int reg = 0; reg < 4; ++reg) {
        int oc = 16 * kt + 4 * lg + reg;
        float v = acc[kt][mt][reg] * scv[mt] + mask[((size_t)oc * NN + m) * CHO + w];
        out[(((size_t)(b * 128 + oc)) * NN + m) * CHO + w] = v;
      }
    }
  }
}

extern "C" void kernel_launch(void* const* d_in, const int* in_sizes, int n_in,
                              void* d_out, int out_size, void* d_ws, size_t ws_size,
                              hipStream_t stream) {
  const float* x     = (const float*)d_in[0];
  const float* Wq    = (const float*)d_in[1];
  const float* Wk    = (const float*)d_in[2];
  const float* Wv    = (const float*)d_in[3];
  const float* gamma = (const float*)d_in[4];
  const float* mask  = (const float*)d_in[5];
  float* out = (float*)d_out;

  unsigned short* fT = (unsigned short*)d_ws;                 // [B][NN][C]  f16
  unsigned short* gT = fT + (size_t)B * NN * C;               // [B][NN][C]  f16
  unsigned short* hv = gT + (size_t)B * NN * C;               // [B][KV][NN] f16

  proj_kernel<<<dim3(3072), 256, 0, stream>>>(x, Wq, Wk, Wv, fT, gT, hv);
  attn_kernel<<<dim3(256), 256, 0, stream>>>(fT, gT, hv, gamma, mask, out);
}